// Round 10
// baseline (364.231 us; speedup 1.0000x reference)
//
#include <hip/hip_runtime.h>
#include <cstdint>

#define DD 128
#define CAP 64
#define LSTR 132   // LDS row stride in u16: 264B rows -> 2-way (free) b64 frag reads
#define E0C 480000
#define E1C 96000
#define N0C 120000
#define N1C 30000
#define N2C 6000

typedef unsigned short u16;
typedef __attribute__((ext_vector_type(8))) short bf16x8;
typedef __attribute__((ext_vector_type(16))) float f32x16;

__device__ __forceinline__ u16 f2b(float f) {
    union { float f; unsigned u; } a; a.f = f;
    unsigned r = (a.u + 0x7fffu + ((a.u >> 16) & 1u)) >> 16;
    return (u16)r;
}
__device__ __forceinline__ float b2f(u16 u) {
    union { unsigned u; float f; } a; a.u = ((unsigned)u) << 16;
    return a.f;
}
__device__ __forceinline__ bf16x8 ldsfrag(const u16* p) {
    union { uint2 u2[2]; bf16x8 v; } u;
    u.u2[0] = *(const uint2*)p;
    u.u2[1] = *(const uint2*)(p + 4);
    return u.v;
}

// ---- K1: weight convert+transpose into MFMA fragment order + zero counters ----
// wt layout (shorts): mat*16384 + kc*2048 + t*512 + half*256 + l31*8 + j
// where n = t*32+l31, k = kc*16+half*8+j.
struct WtJob { const float* src[12]; };
__global__ __launch_bounds__(256) void prep_kernel(
    WtJob job, u16* __restrict__ dst, int* __restrict__ cnt0, int* __restrict__ cnt1)
{
    int gtid = blockIdx.x * 256 + threadIdx.x;
    for (int i = gtid; i < N1C + N2C; i += 256 * 256) {
        if (i < N1C) cnt0[i] = 0; else cnt1[i - N1C] = 0;
    }
    if (blockIdx.x >= 192) return;
    __shared__ float tile[32][33];
    int m = blockIdx.x >> 4;
    int t4 = blockIdx.x & 15;
    int tr = (t4 >> 2) * 32;   // k-base
    int tc = (t4 & 3) * 32;    // n-base
    int lx = threadIdx.x & 31, ly = threadIdx.x >> 5;
    #pragma unroll
    for (int yy = 0; yy < 32; yy += 8)
        tile[ly + yy][lx] = job.src[m][(tr + ly + yy) * DD + tc + lx];
    __syncthreads();
    int tid = threadIdx.x;
    if (tid < 128) {
        int nl = tid >> 2, kch = tid & 3;
        int k = tr + kch * 8, n = tc + nl;
        int kc = k >> 4, half = (k >> 3) & 1;
        int t = n >> 5, l31 = n & 31;
        bf16x8 pk;
        #pragma unroll
        for (int j = 0; j < 8; ++j) pk[j] = (short)f2b(tile[kch * 8 + j][nl]);
        *(bf16x8*)(dst + (size_t)m * 16384 + kc * 2048 + t * 512 + half * 256 + l31 * 8) = pk;
    }
}

// ---- K2: FUSED bucket-fill + pre-GEMM (R8 shape: 4-wave blocks, best measured) ----
__global__ __launch_bounds__(256) void pre_fill_kernel(
    const float* __restrict__ x,
    const int* __restrict__ src0, const int* __restrict__ dst0, const int* __restrict__ eid0,
    const int* __restrict__ src1, const int* __restrict__ dst1, const int* __restrict__ eid1,
    const int* __restrict__ etype,
    int* __restrict__ cnt0, int* __restrict__ cnt1,
    int* __restrict__ ep0, int* __restrict__ ep1,
    const u16* __restrict__ Wr, const float* __restrict__ bias,
    u16* __restrict__ h0)
{
    int gtid = blockIdx.x * 256 + threadIdx.x;
    int nthr = gridDim.x * 256;
    for (int e = gtid; e < E0C + E1C; e += nthr) {
        bool L0 = e < E0C;
        int ee = L0 ? e : e - E0C;
        int d   = L0 ? dst0[ee] : dst1[ee];
        int eid = L0 ? eid0[ee] : eid1[ee];
        int s   = L0 ? src0[ee] : src1[ee];
        int r = etype[eid];
        int* cnt = L0 ? cnt0 : cnt1;
        int* ep  = L0 ? ep0  : ep1;
        int pos = atomicAdd(&cnt[d], 1);
        if (pos < CAP) ep[(size_t)d * CAP + pos] = s | (r << 28);
    }

    int wave = threadIdx.x >> 6;
    int lane = threadIdx.x & 63;
    int l31 = lane & 31, half = lane >> 5;
    int ntile = (N0C + 31) >> 5;
    for (int tile = blockIdx.x * 4 + wave; tile < ntile; tile += gridDim.x * 4) {
        int m0 = tile * 32;
        int arow = m0 + l31;
        bool rv = arow < N0C;
        f32x16 acc;
        #pragma unroll
        for (int i = 0; i < 16; ++i) acc[i] = 0.f;

        const float* Aq = x + (size_t)arow * DD;
        float4 st[16];
        if (rv) {
            #pragma unroll
            for (int c = 0; c < 16; ++c)
                st[c] = *(const float4*)(Aq + ((c >> 1) * 16 + half * 8) + (c & 1) * 4);
        } else {
            #pragma unroll
            for (int c = 0; c < 16; ++c) st[c] = make_float4(0.f, 0.f, 0.f, 0.f);
        }
        f32x16 accs[4];
        #pragma unroll
        for (int t = 0; t < 4; ++t)
            #pragma unroll
            for (int i = 0; i < 16; ++i) accs[t][i] = 0.f;
        #pragma unroll
        for (int kc = 0; kc < 8; ++kc) {
            bf16x8 bfr[4];
            #pragma unroll
            for (int t = 0; t < 4; ++t)
                bfr[t] = *(const bf16x8*)(Wr + (size_t)((kc * 4 + t) * 64 + lane) * 8);
            float4 u0 = st[2 * kc], u1 = st[2 * kc + 1];
            bf16x8 af;
            af[0] = (short)f2b(u0.x); af[1] = (short)f2b(u0.y);
            af[2] = (short)f2b(u0.z); af[3] = (short)f2b(u0.w);
            af[4] = (short)f2b(u1.x); af[5] = (short)f2b(u1.y);
            af[6] = (short)f2b(u1.z); af[7] = (short)f2b(u1.w);
            #pragma unroll
            for (int t = 0; t < 4; ++t)
                accs[t] = __builtin_amdgcn_mfma_f32_32x32x16_bf16(af, bfr[t], accs[t], 0, 0, 0);
        }
        float bb[4];
        #pragma unroll
        for (int t = 0; t < 4; ++t) bb[t] = bias[t * 32 + l31];
        #pragma unroll
        for (int reg = 0; reg < 16; ++reg) {
            int rl = (reg & 3) + 8 * (reg >> 2) + 4 * half;
            int row = m0 + rl;
            if (row < N0C) {
                #pragma unroll
                for (int t = 0; t < 4; ++t)
                    h0[(size_t)row * DD + t * 32 + l31] =
                        f2b(fmaxf(accs[t][reg] + bb[t], 0.f));
            }
        }
    }
}

// ---- K3/K4: FUSED layer kernel: gather-agg (LDS tile) + conv GEMM + LN/ReLU
//      [+ post GEMM for the final layer, h2 never leaves LDS] ----
// Block = 256 thr = 32 dst rows. Wave w gathers rows w*8..w*8+7 into Tt
// (4 planes, bf16, row stride LSTR). GEMM: wave w computes output cols
// w*32..w*32+31 (one 32x32 C-tile, 40 MFMAs). LN reduced across waves in LDS.
// C/D layout: col=lane&31, row=(reg&3)+8*(reg>>2)+4*(lane>>5)  [m74/m101].
template<bool POST>
__global__ __launch_bounds__(256) void layer_kernel(
    const u16* __restrict__ h, const int* __restrict__ cnt,
    const int* __restrict__ ep, const float* __restrict__ comp,
    const u16* __restrict__ Wp, const u16* __restrict__ Wr,
    const float* __restrict__ bias, const float* __restrict__ gw,
    const float* __restrict__ bw,
    const u16* __restrict__ Wpost, const float* __restrict__ postb,
    u16* __restrict__ hout, float* __restrict__ out, int ndst)
{
    __shared__ u16 Tt[4 * 32 * LSTR];
    __shared__ float2 lnb[32][4];
    __shared__ float4 cmp4[8];
    int tid = threadIdx.x;
    int wv = tid >> 6, lane = tid & 63, l31 = lane & 31, half = lane >> 5;
    int m0 = blockIdx.x * 32;
    if (tid < 8) cmp4[tid] = ((const float4*)comp)[tid];
    __syncthreads();

    // ---- gather phase: 8 rows per wave ----
    for (int i = 0; i < 8; ++i) {
        int lr = wv * 8 + i;
        int row = m0 + lr;
        float a0[4] = {0.f, 0.f, 0.f, 0.f};
        float a1[4] = {0.f, 0.f, 0.f, 0.f};
        float inv = 1.f;
        if (row < ndst) {
            int n = cnt[row];
            int end = n < CAP ? n : CAP;
            const int* erow = ep + (size_t)row * CAP;
            int j = 0;
            for (; j + 16 <= end; j += 16) {
                int vv[16]; unsigned gg[16];
                #pragma unroll
                for (int u = 0; u < 16; ++u) vv[u] = erow[j + u];
                #pragma unroll
                for (int u = 0; u < 16; ++u)
                    gg[u] = *(const unsigned*)(h + (size_t)(vv[u] & 0x0FFFFFFF) * DD + 2 * lane);
                #pragma unroll
                for (int u = 0; u < 16; ++u) {
                    float4 c = cmp4[vv[u] >> 28];
                    float x0 = b2f((u16)(gg[u] & 0xffffu));
                    float x1 = b2f((u16)(gg[u] >> 16));
                    a0[0] = fmaf(c.x, x0, a0[0]); a1[0] = fmaf(c.x, x1, a1[0]);
                    a0[1] = fmaf(c.y, x0, a0[1]); a1[1] = fmaf(c.y, x1, a1[1]);
                    a0[2] = fmaf(c.z, x0, a0[2]); a1[2] = fmaf(c.z, x1, a1[2]);
                    a0[3] = fmaf(c.w, x0, a0[3]); a1[3] = fmaf(c.w, x1, a1[3]);
                }
            }
            for (; j < end; ++j) {
                int v = erow[j];
                unsigned g = *(const unsigned*)(h + (size_t)(v & 0x0FFFFFFF) * DD + 2 * lane);
                float4 c = cmp4[v >> 28];
                float x0 = b2f((u16)(g & 0xffffu));
                float x1 = b2f((u16)(g >> 16));
                a0[0] = fmaf(c.x, x0, a0[0]); a1[0] = fmaf(c.x, x1, a1[0]);
                a0[1] = fmaf(c.y, x0, a0[1]); a1[1] = fmaf(c.y, x1, a1[1]);
                a0[2] = fmaf(c.z, x0, a0[2]); a1[2] = fmaf(c.z, x1, a1[2]);
                a0[3] = fmaf(c.w, x0, a0[3]); a1[3] = fmaf(c.w, x1, a1[3]);
            }
            inv = 1.f / fmaxf((float)n, 1.f);
        }
        #pragma unroll
        for (int b = 0; b < 4; ++b) {
            unsigned pk = (unsigned)f2b(a0[b] * inv) | ((unsigned)f2b(a1[b] * inv) << 16);
            *(unsigned*)&Tt[(size_t)(b * 32 + lr) * LSTR + 2 * lane] = pk;
        }
    }

    // root fragments from global h
    int arow = m0 + l31;
    bool rv = arow < ndst;
    bf16x8 R[8];
    if (rv) {
        #pragma unroll
        for (int c = 0; c < 8; ++c)
            R[c] = *(const bf16x8*)(h + (size_t)arow * DD + c * 16 + half * 8);
    } else {
        #pragma unroll
        for (int c = 0; c < 8; ++c) R[c] = (bf16x8){0,0,0,0,0,0,0,0};
    }
    __syncthreads();

    // ---- GEMM: this wave owns cols wv*32 .. wv*32+31 ----
    f32x16 acc;
    #pragma unroll
    for (int i = 0; i < 16; ++i) acc[i] = 0.f;
    for (int p = 0; p < 4; ++p) {
        #pragma unroll
        for (int kc = 0; kc < 8; ++kc) {
            bf16x8 af = ldsfrag(&Tt[(size_t)(p * 32 + l31) * LSTR + kc * 16 + half * 8]);
            bf16x8 bf = *(const bf16x8*)(Wp + (size_t)p * 16384 + ((kc * 4 + wv) * 64 + lane) * 8);
            acc = __builtin_amdgcn_mfma_f32_32x32x16_bf16(af, bf, acc, 0, 0, 0);
        }
    }
    #pragma unroll
    for (int kc = 0; kc < 8; ++kc) {
        bf16x8 bf = *(const bf16x8*)(Wr + ((kc * 4 + wv) * 64 + lane) * 8);
        acc = __builtin_amdgcn_mfma_f32_32x32x16_bf16(R[kc], bf, acc, 0, 0, 0);
    }

    // ---- LN epilogue (cross-wave row reduction) ----
    float bb = bias[wv * 32 + l31];
    float G = gw[wv * 32 + l31];
    float Bt = bw[wv * 32 + l31];
    float v[16];
    #pragma unroll
    for (int reg = 0; reg < 16; ++reg) v[reg] = acc[reg] + bb;
    #pragma unroll
    for (int reg = 0; reg < 16; ++reg) {
        float s1 = v[reg], s2 = v[reg] * v[reg];
        #pragma unroll
        for (int o = 1; o < 32; o <<= 1) {
            s1 += __shfl_xor(s1, o);
            s2 += __shfl_xor(s2, o);
        }
        if (l31 == 0) {
            int rl = (reg & 3) + 8 * (reg >> 2) + 4 * half;
            lnb[rl][wv] = make_float2(s1, s2);
        }
    }
    __syncthreads();
    #pragma unroll
    for (int reg = 0; reg < 16; ++reg) {
        int rl = (reg & 3) + 8 * (reg >> 2) + 4 * half;
        float2 t0 = lnb[rl][0], t1 = lnb[rl][1], t2 = lnb[rl][2], t3 = lnb[rl][3];
        float s1 = t0.x + t1.x + t2.x + t3.x;
        float s2 = t0.y + t1.y + t2.y + t3.y;
        float mu = s1 * (1.f / 128.f);
        float var = s2 * (1.f / 128.f) - mu * mu;
        float rstd = rsqrtf(fmaxf(var, 0.f) + 1e-5f);
        float y = fmaxf((v[reg] - mu) * rstd * G + Bt, 0.f);
        int row = m0 + rl;
        if (POST) {
            Tt[(size_t)rl * LSTR + wv * 32 + l31] = f2b(y);
        } else if (row < ndst) {
            hout[(size_t)row * DD + wv * 32 + l31] = f2b(y);
        }
    }

    if (POST) {
        __syncthreads();
        f32x16 a2;
        #pragma unroll
        for (int i = 0; i < 16; ++i) a2[i] = 0.f;
        #pragma unroll
        for (int kc = 0; kc < 8; ++kc) {
            bf16x8 af = ldsfrag(&Tt[(size_t)l31 * LSTR + kc * 16 + half * 8]);
            bf16x8 bf = *(const bf16x8*)(Wpost + ((kc * 4 + wv) * 64 + lane) * 8);
            a2 = __builtin_amdgcn_mfma_f32_32x32x16_bf16(af, bf, a2, 0, 0, 0);
        }
        float pb = postb[wv * 32 + l31];
        #pragma unroll
        for (int reg = 0; reg < 16; ++reg) {
            int rl = (reg & 3) + 8 * (reg >> 2) + 4 * half;
            int row = m0 + rl;
            if (row < ndst)
                out[(size_t)row * DD + wv * 32 + l31] = a2[reg] + pb;
        }
    }
}

extern "C" void kernel_launch(void* const* d_in, const int* in_sizes, int n_in,
                              void* d_out, int out_size, void* d_ws, size_t ws_size,
                              hipStream_t stream)
{
    const float* x     = (const float*)d_in[0];
    const int* src0    = (const int*)d_in[1];
    const int* dst0    = (const int*)d_in[2];
    const int* eid0    = (const int*)d_in[3];
    const int* src1    = (const int*)d_in[4];
    const int* dst1    = (const int*)d_in[5];
    const int* eid1    = (const int*)d_in[6];
    const int* etype   = (const int*)d_in[7];
    const float* preW  = (const float*)d_in[8];
    const float* preb  = (const float*)d_in[9];
    const float* basis0 = (const float*)d_in[10];
    const float* comp0  = (const float*)d_in[11];
    const float* root0  = (const float*)d_in[12];
    const float* bias0  = (const float*)d_in[13];
    const float* g0    = (const float*)d_in[14];
    const float* be0   = (const float*)d_in[15];
    const float* basis1 = (const float*)d_in[16];
    const float* comp1  = (const float*)d_in[17];
    const float* root1  = (const float*)d_in[18];
    const float* bias1  = (const float*)d_in[19];
    const float* g1    = (const float*)d_in[20];
    const float* be1   = (const float*)d_in[21];
    const float* postW = (const float*)d_in[22];
    const float* postb = (const float*)d_in[23];
    float* out = (float*)d_out;

    char* ws = (char*)d_ws;
    size_t o = 0;
    auto alloc = [&](size_t bytes) { char* p = ws + o; o += (bytes + 255) & ~(size_t)255; return p; };
    u16* h0   = (u16*)alloc((size_t)N0C * DD * 2);
    u16* h1   = (u16*)alloc((size_t)N1C * DD * 2);
    u16* wt   = (u16*)alloc((size_t)12 * 16384 * 2);
    int* cnt0 = (int*)alloc((size_t)N1C * 4);
    int* cnt1 = (int*)alloc((size_t)N2C * 4);
    int* ep0  = (int*)alloc((size_t)N1C * CAP * 4);
    int* ep1  = (int*)alloc((size_t)N2C * CAP * 4);

    // wt layout: [0]=pre, [1..4]=basis0, [5]=root0, [6..9]=basis1, [10]=root1, [11]=post
    WtJob job;
    job.src[0] = preW;
    for (int b = 0; b < 4; ++b) job.src[1 + b] = basis0 + (size_t)b * 16384;
    job.src[5] = root0;
    for (int b = 0; b < 4; ++b) job.src[6 + b] = basis1 + (size_t)b * 16384;
    job.src[10] = root1;
    job.src[11] = postW;

    // K1: weight transpose + zero counters
    prep_kernel<<<256, 256, 0, stream>>>(job, wt, cnt0, cnt1);
    // K2: fused bucket-fill + pre-GEMM (R8 shape)
    pre_fill_kernel<<<(N0C + 127) / 128, 256, 0, stream>>>(
        x, src0, dst0, eid0, src1, dst1, eid1, etype,
        cnt0, cnt1, ep0, ep1, wt + 0 * 16384, preb, h0);
    // K3: fused agg0 + conv0 + LN + ReLU -> h1
    layer_kernel<false><<<(N1C + 31) / 32, 256, 0, stream>>>(
        h0, cnt0, ep0, comp0, wt + 1 * 16384, wt + 5 * 16384,
        bias0, g0, be0, nullptr, nullptr, h1, nullptr, N1C);
    // K4: fused agg1 + conv1 + LN + ReLU + post-GEMM -> out
    layer_kernel<true><<<(N2C + 31) / 32, 256, 0, stream>>>(
        h1, cnt1, ep1, comp1, wt + 6 * 16384, wt + 10 * 16384,
        bias1, g1, be1, wt + 11 * 16384, postb, nullptr, out, N2C);
}

// Round 11
// 294.807 us; speedup vs baseline: 1.2355x; 1.2355x over previous
//
#include <hip/hip_runtime.h>
#include <cstdint>

#define DD 128
#define CAP 64
#define ESB 128          // edge-specialized blocks co-resident with GEMM blocks
#define E0C 480000
#define E1C 96000
#define N0C 120000
#define N1C 30000
#define N2C 6000

typedef unsigned short u16;
typedef __attribute__((ext_vector_type(8))) short bf16x8;
typedef __attribute__((ext_vector_type(16))) float f32x16;

__device__ __forceinline__ u16 f2b(float f) {
    union { float f; unsigned u; } a; a.f = f;
    unsigned r = (a.u + 0x7fffu + ((a.u >> 16) & 1u)) >> 16;
    return (u16)r;
}
__device__ __forceinline__ float b2f(u16 u) {
    union { unsigned u; float f; } a; a.u = ((unsigned)u) << 16;
    return a.f;
}

// ---- K1: weight convert+transpose into MFMA fragment order + zero counters ----
// wt layout (shorts): mat*16384 + kc*2048 + t*512 + half*256 + l31*8 + j
// where n = t*32+l31, k = kc*16+half*8+j. B-frag load in GEMM is then
// base + ((kc*4+t)*64 + lane)*8 -> lane-consecutive 16B, perfectly coalesced.
struct WtJob { const float* src[12]; };
__global__ __launch_bounds__(256) void prep_kernel(
    WtJob job, u16* __restrict__ dst, int* __restrict__ cnt0, int* __restrict__ cnt1)
{
    int gtid = blockIdx.x * 256 + threadIdx.x;
    for (int i = gtid; i < N1C + N2C; i += 256 * 256) {
        if (i < N1C) cnt0[i] = 0; else cnt1[i - N1C] = 0;
    }
    if (blockIdx.x >= 192) return;
    __shared__ float tile[32][33];
    int m = blockIdx.x >> 4;
    int t4 = blockIdx.x & 15;
    int tr = (t4 >> 2) * 32;   // k-base
    int tc = (t4 & 3) * 32;    // n-base
    int lx = threadIdx.x & 31, ly = threadIdx.x >> 5;
    #pragma unroll
    for (int yy = 0; yy < 32; yy += 8)
        tile[ly + yy][lx] = job.src[m][(tr + ly + yy) * DD + tc + lx];
    __syncthreads();
    int tid = threadIdx.x;
    if (tid < 128) {
        int nl = tid >> 2, kch = tid & 3;
        int k = tr + kch * 8, n = tc + nl;
        int kc = k >> 4, half = (k >> 3) & 1;
        int t = n >> 5, l31 = n & 31;
        bf16x8 pk;
        #pragma unroll
        for (int j = 0; j < 8; ++j) pk[j] = (short)f2b(tile[kch * 8 + j][nl]);
        *(bf16x8*)(dst + (size_t)m * 16384 + kc * 2048 + t * 512 + half * 256 + l31 * 8) = pk;
    }
}

// ---- K2: block-specialized fill + pre-GEMM in ONE dispatch ----
// Blocks [0, ESB): batched edge fill (latency-bound). Blocks [ESB, ...):
// pre-GEMM tiles (BW-bound). Co-residency on each CU overlaps the two.
__global__ __launch_bounds__(256) void pre_fill_kernel(
    const float* __restrict__ x,
    const int* __restrict__ src0, const int* __restrict__ dst0, const int* __restrict__ eid0,
    const int* __restrict__ src1, const int* __restrict__ dst1, const int* __restrict__ eid1,
    const int* __restrict__ etype,
    int* __restrict__ cnt0, int* __restrict__ cnt1,
    int* __restrict__ ep0, int* __restrict__ ep1,
    const u16* __restrict__ Wr, const float* __restrict__ bias,
    u16* __restrict__ h0)
{
    if (blockIdx.x < ESB) {
        // ---- edge fill, 4-way batched for memory-level parallelism ----
        const int STR = ESB * 256;
        int gtid = blockIdx.x * 256 + threadIdx.x;
        int e = gtid;
        for (; e + 3 * STR < E0C + E1C; e += 4 * STR) {
            int d[4], eidv[4], s[4], r[4], pos[4];
            bool L0[4];
            #pragma unroll
            for (int u = 0; u < 4; ++u) {
                int idx = e + u * STR;
                L0[u] = idx < E0C;
                int ee = L0[u] ? idx : idx - E0C;
                d[u]    = L0[u] ? dst0[ee] : dst1[ee];
                eidv[u] = L0[u] ? eid0[ee] : eid1[ee];
                s[u]    = L0[u] ? src0[ee] : src1[ee];
            }
            #pragma unroll
            for (int u = 0; u < 4; ++u) r[u] = etype[eidv[u]];
            #pragma unroll
            for (int u = 0; u < 4; ++u)
                pos[u] = atomicAdd(L0[u] ? &cnt0[d[u]] : &cnt1[d[u]], 1);
            #pragma unroll
            for (int u = 0; u < 4; ++u) {
                if (pos[u] < CAP) {
                    int* ep = L0[u] ? ep0 : ep1;
                    ep[(size_t)d[u] * CAP + pos[u]] = s[u] | (r[u] << 28);
                }
            }
        }
        for (; e < E0C + E1C; e += STR) {
            bool L0 = e < E0C;
            int ee = L0 ? e : e - E0C;
            int d   = L0 ? dst0[ee] : dst1[ee];
            int eid = L0 ? eid0[ee] : eid1[ee];
            int s   = L0 ? src0[ee] : src1[ee];
            int r = etype[eid];
            int pos = atomicAdd(L0 ? &cnt0[d] : &cnt1[d], 1);
            if (pos < CAP) (L0 ? ep0 : ep1)[(size_t)d * CAP + pos] = s | (r << 28);
        }
        return;
    }

    // ---- pre-GEMM: one 32-row tile per wave ----
    int bid = blockIdx.x - ESB;
    int wave = threadIdx.x >> 6;
    int lane = threadIdx.x & 63;
    int l31 = lane & 31, half = lane >> 5;
    int m0 = (bid * 4 + wave) * 32;
    if (m0 >= N0C) return;
    int arow = m0 + l31;
    bool rv = arow < N0C;

    const float* Aq = x + (size_t)arow * DD;
    float4 st[16];
    if (rv) {
        #pragma unroll
        for (int c = 0; c < 16; ++c)
            st[c] = *(const float4*)(Aq + ((c >> 1) * 16 + half * 8) + (c & 1) * 4);
    } else {
        #pragma unroll
        for (int c = 0; c < 16; ++c) st[c] = make_float4(0.f, 0.f, 0.f, 0.f);
    }
    f32x16 accs[4];
    #pragma unroll
    for (int t = 0; t < 4; ++t)
        #pragma unroll
        for (int i = 0; i < 16; ++i) accs[t][i] = 0.f;
    #pragma unroll
    for (int kc = 0; kc < 8; ++kc) {
        bf16x8 bfr[4];
        #pragma unroll
        for (int t = 0; t < 4; ++t)
            bfr[t] = *(const bf16x8*)(Wr + (size_t)((kc * 4 + t) * 64 + lane) * 8);
        float4 u0 = st[2 * kc], u1 = st[2 * kc + 1];
        bf16x8 af;
        af[0] = (short)f2b(u0.x); af[1] = (short)f2b(u0.y);
        af[2] = (short)f2b(u0.z); af[3] = (short)f2b(u0.w);
        af[4] = (short)f2b(u1.x); af[5] = (short)f2b(u1.y);
        af[6] = (short)f2b(u1.z); af[7] = (short)f2b(u1.w);
        #pragma unroll
        for (int t = 0; t < 4; ++t)
            accs[t] = __builtin_amdgcn_mfma_f32_32x32x16_bf16(af, bfr[t], accs[t], 0, 0, 0);
    }
    float bb[4];
    #pragma unroll
    for (int t = 0; t < 4; ++t) bb[t] = bias[t * 32 + l31];
    #pragma unroll
    for (int reg = 0; reg < 16; ++reg) {
        int rl = (reg & 3) + 8 * (reg >> 2) + 4 * half;
        int row = m0 + rl;
        if (row < N0C) {
            #pragma unroll
            for (int t = 0; t < 4; ++t)
                h0[(size_t)row * DD + t * 32 + l31] =
                    f2b(fmaxf(accs[t][reg] + bb[t], 0.f));
        }
    }
}

// ---- gather-aggregate into 4 basis planes, 1/deg folded in, 16-deep pipeline ----
__global__ __launch_bounds__(256) void agg_kernel(
    const u16* __restrict__ h, const int* __restrict__ cnt,
    const int* __restrict__ ep, const float* __restrict__ comp,
    u16* __restrict__ T, int ndst)
{
    __shared__ float4 cmp4[8];
    if (threadIdx.x < 8) cmp4[threadIdx.x] = ((const float4*)comp)[threadIdx.x];
    __syncthreads();
    int row = blockIdx.x * 4 + (threadIdx.x >> 6);
    if (row >= ndst) return;
    int lane = threadIdx.x & 63;
    int n = cnt[row];
    int end = n < CAP ? n : CAP;
    const int* erow = ep + (size_t)row * CAP;
    float a0[4] = {0.f, 0.f, 0.f, 0.f};
    float a1[4] = {0.f, 0.f, 0.f, 0.f};
    int j = 0;
    for (; j + 16 <= end; j += 16) {
        int vv[16]; unsigned gg[16];
        #pragma unroll
        for (int u = 0; u < 16; ++u) vv[u] = erow[j + u];
        #pragma unroll
        for (int u = 0; u < 16; ++u)
            gg[u] = *(const unsigned*)(h + (size_t)(vv[u] & 0x0FFFFFFF) * DD + 2 * lane);
        #pragma unroll
        for (int u = 0; u < 16; ++u) {
            float4 c = cmp4[vv[u] >> 28];
            float x0 = b2f((u16)(gg[u] & 0xffffu));
            float x1 = b2f((u16)(gg[u] >> 16));
            a0[0] = fmaf(c.x, x0, a0[0]); a1[0] = fmaf(c.x, x1, a1[0]);
            a0[1] = fmaf(c.y, x0, a0[1]); a1[1] = fmaf(c.y, x1, a1[1]);
            a0[2] = fmaf(c.z, x0, a0[2]); a1[2] = fmaf(c.z, x1, a1[2]);
            a0[3] = fmaf(c.w, x0, a0[3]); a1[3] = fmaf(c.w, x1, a1[3]);
        }
    }
    for (; j + 4 <= end; j += 4) {
        int vv[4]; unsigned gg[4];
        #pragma unroll
        for (int u = 0; u < 4; ++u) vv[u] = erow[j + u];
        #pragma unroll
        for (int u = 0; u < 4; ++u)
            gg[u] = *(const unsigned*)(h + (size_t)(vv[u] & 0x0FFFFFFF) * DD + 2 * lane);
        #pragma unroll
        for (int u = 0; u < 4; ++u) {
            float4 c = cmp4[vv[u] >> 28];
            float x0 = b2f((u16)(gg[u] & 0xffffu));
            float x1 = b2f((u16)(gg[u] >> 16));
            a0[0] = fmaf(c.x, x0, a0[0]); a1[0] = fmaf(c.x, x1, a1[0]);
            a0[1] = fmaf(c.y, x0, a0[1]); a1[1] = fmaf(c.y, x1, a1[1]);
            a0[2] = fmaf(c.z, x0, a0[2]); a1[2] = fmaf(c.z, x1, a1[2]);
            a0[3] = fmaf(c.w, x0, a0[3]); a1[3] = fmaf(c.w, x1, a1[3]);
        }
    }
    for (; j < end; ++j) {
        int v = erow[j];
        unsigned g = *(const unsigned*)(h + (size_t)(v & 0x0FFFFFFF) * DD + 2 * lane);
        float4 c = cmp4[v >> 28];
        float x0 = b2f((u16)(g & 0xffffu));
        float x1 = b2f((u16)(g >> 16));
        a0[0] = fmaf(c.x, x0, a0[0]); a1[0] = fmaf(c.x, x1, a1[0]);
        a0[1] = fmaf(c.y, x0, a0[1]); a1[1] = fmaf(c.y, x1, a1[1]);
        a0[2] = fmaf(c.z, x0, a0[2]); a1[2] = fmaf(c.z, x1, a1[2]);
        a0[3] = fmaf(c.w, x0, a0[3]); a1[3] = fmaf(c.w, x1, a1[3]);
    }
    float inv = 1.f / fmaxf((float)n, 1.f);
    #pragma unroll
    for (int b = 0; b < 4; ++b) {
        unsigned pk = (unsigned)f2b(a0[b] * inv) | ((unsigned)f2b(a1[b] * inv) << 16);
        *(unsigned*)(T + ((size_t)b * ndst + row) * DD + 2 * lane) = pk;
    }
}

// ---- 32x32x16 MFMA GEMM, one 32-row m-tile per wave, A prefetched ----
// C[nrows x 128] = sum_p Ap[p]@Wp[p] + Ar@Wr + bias, optional LN/ReLU.
// W in fragment order (see prep). A: [row][k].
// C/D layout: col=lane&31, row=(reg&3)+8*(reg>>2)+4*(lane>>5)  [m74/m101].
template<bool OBF16, bool LN>
__global__ __launch_bounds__(64) void mfma_gemm(
    const u16* __restrict__ Ap, int nplanes, const u16* __restrict__ Ar,
    const u16* __restrict__ Wp, const u16* __restrict__ Wr,
    const float* __restrict__ bias, const float* __restrict__ gw,
    const float* __restrict__ bw, void* __restrict__ Cv, int nrows)
{
    int lane = threadIdx.x & 63;
    int l31 = lane & 31, half = lane >> 5;
    int m0 = blockIdx.x * 32;
    int arow = m0 + l31;
    bool rv = arow < nrows;
    f32x16 acc[4];
    #pragma unroll
    for (int t = 0; t < 4; ++t)
        #pragma unroll
        for (int i = 0; i < 16; ++i) acc[t][i] = 0.f;

    bf16x8 A0[8], A1[8];
    {
        const u16* Ainit = (nplanes == 0) ? Ar : Ap;
        if (rv) {
            #pragma unroll
            for (int c = 0; c < 8; ++c)
                A0[c] = *(const bf16x8*)(Ainit + (size_t)arow * DD + c * 16 + half * 8);
        } else {
            #pragma unroll
            for (int c = 0; c < 8; ++c) A0[c] = (bf16x8){0,0,0,0,0,0,0,0};
        }
    }
    for (int p = 0; p <= nplanes; ++p) {
        const u16* Wsel = (p == nplanes) ? Wr : Wp + p * 16384;
        if (p < nplanes) {
            const u16* An = (p + 1 == nplanes) ? Ar : Ap + (size_t)(p + 1) * nrows * DD;
            if (rv) {
                #pragma unroll
                for (int c = 0; c < 8; ++c)
                    A1[c] = *(const bf16x8*)(An + (size_t)arow * DD + c * 16 + half * 8);
            } else {
                #pragma unroll
                for (int c = 0; c < 8; ++c) A1[c] = (bf16x8){0,0,0,0,0,0,0,0};
            }
        }
        #pragma unroll
        for (int kc = 0; kc < 8; ++kc) {
            bf16x8 bfr[4];
            #pragma unroll
            for (int t = 0; t < 4; ++t)
                bfr[t] = *(const bf16x8*)(Wsel + (size_t)((kc * 4 + t) * 64 + lane) * 8);
            #pragma unroll
            for (int t = 0; t < 4; ++t)
                acc[t] = __builtin_amdgcn_mfma_f32_32x32x16_bf16(A0[kc], bfr[t], acc[t], 0, 0, 0);
        }
        if (p < nplanes) {
            #pragma unroll
            for (int c = 0; c < 8; ++c) A0[c] = A1[c];
        }
    }

    float bb[4];
    #pragma unroll
    for (int t = 0; t < 4; ++t) bb[t] = bias[t * 32 + l31];
    float gg[4], ww[4];
    if (LN) {
        #pragma unroll
        for (int t = 0; t < 4; ++t) { gg[t] = gw[t * 32 + l31]; ww[t] = bw[t * 32 + l31]; }
    }

    #pragma unroll
    for (int reg = 0; reg < 16; ++reg) {
        int rl = (reg & 3) + 8 * (reg >> 2) + 4 * half;
        int row = m0 + rl;
        float v[4];
        #pragma unroll
        for (int t = 0; t < 4; ++t) v[t] = acc[t][reg] + bb[t];
        if (LN) {
            float s1 = 0.f, s2 = 0.f;
            #pragma unroll
            for (int t = 0; t < 4; ++t) { s1 += v[t]; s2 += v[t] * v[t]; }
            #pragma unroll
            for (int o = 1; o < 32; o <<= 1) {
                s1 += __shfl_xor(s1, o);
                s2 += __shfl_xor(s2, o);
            }
            float mu = s1 * (1.f / 128.f);
            float var = s2 * (1.f / 128.f) - mu * mu;
            float rstd = rsqrtf(fmaxf(var, 0.f) + 1e-5f);
            #pragma unroll
            for (int t = 0; t < 4; ++t)
                v[t] = fmaxf((v[t] - mu) * rstd * gg[t] + ww[t], 0.f);
        }
        if (row < nrows) {
            #pragma unroll
            for (int t = 0; t < 4; ++t) {
                if (OBF16) ((u16*)Cv)[(size_t)row * DD + t * 32 + l31] = f2b(v[t]);
                else       ((float*)Cv)[(size_t)row * DD + t * 32 + l31] = v[t];
            }
        }
    }
}

extern "C" void kernel_launch(void* const* d_in, const int* in_sizes, int n_in,
                              void* d_out, int out_size, void* d_ws, size_t ws_size,
                              hipStream_t stream)
{
    const float* x     = (const float*)d_in[0];
    const int* src0    = (const int*)d_in[1];
    const int* dst0    = (const int*)d_in[2];
    const int* eid0    = (const int*)d_in[3];
    const int* src1    = (const int*)d_in[4];
    const int* dst1    = (const int*)d_in[5];
    const int* eid1    = (const int*)d_in[6];
    const int* etype   = (const int*)d_in[7];
    const float* preW  = (const float*)d_in[8];
    const float* preb  = (const float*)d_in[9];
    const float* basis0 = (const float*)d_in[10];
    const float* comp0  = (const float*)d_in[11];
    const float* root0  = (const float*)d_in[12];
    const float* bias0  = (const float*)d_in[13];
    const float* g0    = (const float*)d_in[14];
    const float* be0   = (const float*)d_in[15];
    const float* basis1 = (const float*)d_in[16];
    const float* comp1  = (const float*)d_in[17];
    const float* root1  = (const float*)d_in[18];
    const float* bias1  = (const float*)d_in[19];
    const float* g1    = (const float*)d_in[20];
    const float* be1   = (const float*)d_in[21];
    const float* postW = (const float*)d_in[22];
    const float* postb = (const float*)d_in[23];
    float* out = (float*)d_out;

    char* ws = (char*)d_ws;
    size_t o = 0;
    auto alloc = [&](size_t bytes) { char* p = ws + o; o += (bytes + 255) & ~(size_t)255; return p; };
    u16* h0   = (u16*)alloc((size_t)N0C * DD * 2);
    u16* T0   = (u16*)alloc((size_t)4 * N1C * DD * 2);
    u16* h1   = (u16*)alloc((size_t)N1C * DD * 2);
    u16* T1   = (u16*)alloc((size_t)4 * N2C * DD * 2);
    u16* h2   = (u16*)alloc((size_t)N2C * DD * 2);
    u16* wt   = (u16*)alloc((size_t)12 * 16384 * 2);
    int* cnt0 = (int*)alloc((size_t)N1C * 4);
    int* cnt1 = (int*)alloc((size_t)N2C * 4);
    int* ep0  = (int*)alloc((size_t)N1C * CAP * 4);
    int* ep1  = (int*)alloc((size_t)N2C * CAP * 4);

    // wt layout: [0]=pre, [1..4]=basis0, [5]=root0, [6..9]=basis1, [10]=root1, [11]=post
    WtJob job;
    job.src[0] = preW;
    for (int b = 0; b < 4; ++b) job.src[1 + b] = basis0 + (size_t)b * 16384;
    job.src[5] = root0;
    for (int b = 0; b < 4; ++b) job.src[6 + b] = basis1 + (size_t)b * 16384;
    job.src[10] = root1;
    job.src[11] = postW;

    // K1: weight transpose + zero counters
    prep_kernel<<<256, 256, 0, stream>>>(job, wt, cnt0, cnt1);
    // K2: block-specialized fill + pre-GEMM (ESB edge blocks + 938 GEMM blocks)
    pre_fill_kernel<<<ESB + (N0C + 127) / 128, 256, 0, stream>>>(
        x, src0, dst0, eid0, src1, dst1, eid1, etype,
        cnt0, cnt1, ep0, ep1, wt + 0 * 16384, preb, h0);
    // K3: agg layer 0
    agg_kernel<<<(N1C + 3) / 4, 256, 0, stream>>>(h0, cnt0, ep0, comp0, T0, N1C);
    // K4: conv0 + LN + ReLU  (938 single-wave blocks)
    mfma_gemm<true, true><<<(N1C + 31) / 32, 64, 0, stream>>>(
        T0, 4, h0, wt + 1 * 16384, wt + 5 * 16384, bias0, g0, be0, h1, N1C);
    // K5: agg layer 1
    agg_kernel<<<(N2C + 3) / 4, 256, 0, stream>>>(h1, cnt1, ep1, comp1, T1, N2C);
    // K6: conv1 + LN + ReLU
    mfma_gemm<true, true><<<(N2C + 31) / 32, 64, 0, stream>>>(
        T1, 4, h1, wt + 6 * 16384, wt + 10 * 16384, bias1, g1, be1, h2, N2C);
    // K7: out = h2 @ postW + postb
    mfma_gemm<false, false><<<(N2C + 31) / 32, 64, 0, stream>>>(
        nullptr, 0, h2, nullptr, wt + 11 * 16384, postb, nullptr, nullptr, out, N2C);
}